// Round 12
// baseline (376.495 us; speedup 1.0000x reference)
//
#include <hip/hip_runtime.h>
#include <math.h>

#define BB 4
#define NN 4096
#define KNNK 16
#define DD 128
#define BN (BB*NN)

typedef __attribute__((ext_vector_type(8))) short short8;   // 8 bf16
typedef __attribute__((ext_vector_type(4))) float floatx4;  // MFMA acc

// Compiler-native bf16 convert (RNE; verified round 10).
__device__ __forceinline__ short f2bf(float x) {
  __bf16 b = (__bf16)x;
  return (short)__builtin_bit_cast(unsigned short, b);
}

__device__ __forceinline__ float bf2f(short h) {
  return __uint_as_float((unsigned)(unsigned short)h << 16);
}

// Per-wave LDS fence (conv[] is wave-private; verified round 3/5/7).
#define LDSFENCE() asm volatile("s_waitcnt lgkmcnt(0)" ::: "memory")

// ---------------------------------------------------------------------------
// Shared split-bf16 GEMM helpers (verified structure).
// ---------------------------------------------------------------------------
__device__ __forceinline__ void split_from_lds(const float* __restrict__ trans,
                                               int c, int g, short8 ah[4],
                                               short8 al[4]) {
#pragma unroll
  for (int s = 0; s < 4; ++s) {
    const float* p_ = &trans[c * 132 + s * 32 + g * 8];
    float4 u0 = *reinterpret_cast<const float4*>(p_);
    float4 u1 = *reinterpret_cast<const float4*>(p_ + 4);
    float tmp[8] = {u0.x, u0.y, u0.z, u0.w, u1.x, u1.y, u1.z, u1.w};
#pragma unroll
    for (int j = 0; j < 8; ++j) {
      short h_ = f2bf(tmp[j]);
      ah[s][j] = h_;
      al[s][j] = f2bf(tmp[j] - bf2f(h_));
    }
  }
}

__device__ __forceinline__ void split_gemm2(const short* __restrict__ Bh,
                                            int nt0, int lane,
                                            const short8 ah[4],
                                            const short8 al[4], floatx4& acc0,
                                            floatx4& acc1) {
  const short* Bl = Bh + 16384;
#pragma unroll
  for (int ks = 0; ks < 4; ++ks) {
    const size_t o0 = ((size_t)((nt0 + 0) * 4 + ks) * 64 + lane) * 8;
    const size_t o1 = ((size_t)((nt0 + 1) * 4 + ks) * 64 + lane) * 8;
    short8 bh0 = *reinterpret_cast<const short8*>(Bh + o0);
    short8 bl0 = *reinterpret_cast<const short8*>(Bl + o0);
    short8 bh1 = *reinterpret_cast<const short8*>(Bh + o1);
    short8 bl1 = *reinterpret_cast<const short8*>(Bl + o1);
    acc0 = __builtin_amdgcn_mfma_f32_16x16x32_bf16(ah[ks], bh0, acc0, 0, 0, 0);
    acc1 = __builtin_amdgcn_mfma_f32_16x16x32_bf16(ah[ks], bh1, acc1, 0, 0, 0);
    acc0 = __builtin_amdgcn_mfma_f32_16x16x32_bf16(ah[ks], bl0, acc0, 0, 0, 0);
    acc1 = __builtin_amdgcn_mfma_f32_16x16x32_bf16(ah[ks], bl1, acc1, 0, 0, 0);
    acc0 = __builtin_amdgcn_mfma_f32_16x16x32_bf16(al[ks], bh0, acc0, 0, 0, 0);
    acc1 = __builtin_amdgcn_mfma_f32_16x16x32_bf16(al[ks], bh1, acc1, 0, 0, 0);
  }
}

// ---------------------------------------------------------------------------
// KNN v6 (verified round 10): 4 queries/wave, float4 pts4 loads.
// Standalone kernel — round-8 fusion regressed 2x; do not re-fuse.
// ---------------------------------------------------------------------------
__device__ __forceinline__ void ced(double& a, double& b) {
  double mn = fmin(a, b);
  double mx = fmax(a, b);
  a = mn;
  b = mx;
}

__device__ __forceinline__ void dsort16(double v[16]) {
#define CE(i, j) ced(v[i], v[j]);
  CE(0, 1) CE(2, 3) CE(4, 5) CE(6, 7) CE(8, 9) CE(10, 11) CE(12, 13) CE(14, 15)
  CE(0, 2) CE(1, 3) CE(4, 6) CE(5, 7) CE(8, 10) CE(9, 11) CE(12, 14) CE(13, 15)
  CE(1, 2) CE(5, 6) CE(9, 10) CE(13, 14)
  CE(0, 4) CE(1, 5) CE(2, 6) CE(3, 7) CE(8, 12) CE(9, 13) CE(10, 14) CE(11, 15)
  CE(2, 4) CE(3, 5) CE(10, 12) CE(11, 13)
  CE(1, 2) CE(3, 4) CE(5, 6) CE(9, 10) CE(11, 12) CE(13, 14)
  CE(0, 8) CE(1, 9) CE(2, 10) CE(3, 11) CE(4, 12) CE(5, 13) CE(6, 14) CE(7, 15)
  CE(4, 8) CE(5, 9) CE(6, 10) CE(7, 11)
  CE(2, 4) CE(3, 5) CE(6, 8) CE(7, 9) CE(10, 12) CE(11, 13)
  CE(1, 2) CE(3, 4) CE(5, 6) CE(7, 8) CE(9, 10) CE(11, 12) CE(13, 14)
#undef CE
}

// sort a 16-element bitonic sequence ascending
__device__ __forceinline__ void dbitonic16(double m[16]) {
#pragma unroll
  for (int s = 8; s >= 1; s >>= 1) {
#pragma unroll
    for (int i = 0; i < 16; ++i) {
      if ((i & s) == 0) ced(m[i], m[i + s]);
    }
  }
}

__global__ __launch_bounds__(256, 4) void knn_kernel(
    const float4* __restrict__ pts4, int* __restrict__ knn) {
  const int wv = threadIdx.x >> 6;
  const int lane = threadIdx.x & 63;
  const int ln = lane & 15;   // lane within 16-lane query group
  const int qg = lane >> 4;   // query group 0..3 within wave
  const int q = blockIdx.x * 16 + wv * 4 + qg;
  const int b = q >> 12;
  const int n = q & 4095;
  const float4* pb = pts4 + ((size_t)b << 12);

  const float4 qp = pb[n];
  const float qx = qp.x, qy = qp.y, qz = qp.z, qsq = qp.w;

#define LOADBATCH(batch)                                                       \
  _Pragma("unroll") for (int i = 0; i < 16; ++i) {                             \
    const int c = ((batch) * 16 + i) * 16 + ln;                                \
    float4 p = pb[c];                                                          \
    float dot = __fadd_rn(__fadd_rn(__fmul_rn(qx, p.x), __fmul_rn(qy, p.y)),   \
                          __fmul_rn(qz, p.z));                                 \
    float d = __fadd_rn(__fsub_rn(qsq, __fmul_rn(2.0f, dot)), p.w);            \
    unsigned u = __float_as_uint(d);                                           \
    u = (u & 0x80000000u) ? ~u : (u | 0x80000000u);                            \
    unsigned long long key =                                                   \
        0x3FF0000000000000ULL | (((unsigned long long)u << 12) | (unsigned)c); \
    v[i] = __longlong_as_double((long long)key);                               \
  }

  double top[16];
  {
    double v[16];
    LOADBATCH(0);
    dsort16(v);
#pragma unroll
    for (int i = 0; i < 16; ++i) top[i] = v[i];
  }
#pragma unroll 1
  for (int batch = 1; batch < 16; ++batch) {
    double v[16];
    LOADBATCH(batch);
    dsort16(v);
    double m[16];
#pragma unroll
    for (int i = 0; i < 16; ++i)
      m[i] = fmin(top[i], v[15 - i]);  // min(asc, desc) -> bitonic lower half
    dbitonic16(m);
#pragma unroll
    for (int i = 0; i < 16; ++i) top[i] = m[i];
  }
#undef LOADBATCH

  // cross-lane merge within the 16-lane query group (masks 1,2,4,8)
#pragma unroll
  for (int mask = 1; mask <= 8; mask <<= 1) {
    double oth[16];
#pragma unroll
    for (int i = 0; i < 16; ++i) {
      double y = __shfl_xor(top[15 - i], mask);
      oth[i] = fmin(y, top[i]);
    }
    dbitonic16(oth);
#pragma unroll
    for (int i = 0; i < 16; ++i) top[i] = oth[i];
  }

  if (ln == 0) {
    int* outp = knn + (size_t)q * KNNK;
#pragma unroll
    for (int k = 0; k < 16; ++k)
      outp[k] = (int)(__double_as_longlong(top[k]) & 0xFFFLL);
  }
}

// ---------------------------------------------------------------------------
// Combined weight pre-swizzle + pts4 precompute (verified, round-10 exact).
// ---------------------------------------------------------------------------
__global__ void swz_all_kernel(const float* __restrict__ xyz,
                               const float* __restrict__ Wd2,
                               const float* __restrict__ Wg1,
                               const float* __restrict__ Wg2,
                               const float* __restrict__ W0b,
                               const float* __restrict__ W1,
                               const float* __restrict__ Wq,
                               const float* __restrict__ Wk,
                               const float* __restrict__ Wv,
                               const float* __restrict__ W2,
                               short* __restrict__ wsw,
                               short* __restrict__ wsplit,
                               float4* __restrict__ pts4) {
  int t = blockIdx.x * 256 + threadIdx.x;
  if (t < BN) {
    float cx = xyz[(size_t)t * 3 + 0];
    float cy = xyz[(size_t)t * 3 + 1];
    float cz = xyz[(size_t)t * 3 + 2];
    float csq = __fadd_rn(__fadd_rn(__fmul_rn(cx, cx), __fmul_rn(cy, cy)),
                          __fmul_rn(cz, cz));
    pts4[t] = make_float4(cx, cy, cz, csq);
  }
  if (t < 3 * 2048) {
    int stage = t / 2048;
    int rem = t % 2048;
    int nt = rem / 256;
    int ks = (rem % 256) / 64;
    int lane = rem % 64;
    const float* W = (stage == 0) ? Wd2 : (stage == 1) ? Wg1 : Wg2;
    short8 o;
#pragma unroll
    for (int j = 0; j < 8; ++j) {
      int k = ks * 32 + (lane >> 4) * 8 + j;
      int n = nt * 16 + (lane & 15);
      o[j] = f2bf(W[k * 128 + n]);
    }
    *reinterpret_cast<short8*>(wsw + (size_t)t * 8) = o;
  } else {
    int u = t - 3 * 2048;
    if (u >= 6 * 2048) return;
    int mat = u / 2048;
    int rem = u % 2048;
    int nt = rem / 256;
    int ks = (rem % 256) / 64;
    int lane = rem % 64;
    const float* W = (mat == 0) ? W0b : (mat == 1) ? W1 : (mat == 2) ? Wq
                     : (mat == 3) ? Wk : (mat == 4) ? Wv : W2;
    short8 hi, lo;
#pragma unroll
    for (int j = 0; j < 8; ++j) {
      int k = ks * 32 + (lane >> 4) * 8 + j;
      int n = nt * 16 + (lane & 15);
      float w = W[k * 128 + n];
      short h = f2bf(w);
      hi[j] = h;
      lo[j] = f2bf(w - bf2f(h));
    }
    *reinterpret_cast<short8*>(wsplit + ((size_t)(2 * mat) * 2048 + rem) * 8) = hi;
    *reinterpret_cast<short8*>(wsplit + ((size_t)(2 * mat + 1) * 2048 + rem) * 8) = lo;
  }
}

// ---------------------------------------------------------------------------
// Point-MLP on matrix cores (verified, round-5/7/9/10 exact).
// ---------------------------------------------------------------------------
__global__ __launch_bounds__(256, 4) void point_mlp_mfma_kernel(
    const float* __restrict__ xyz, const float* __restrict__ W0a,
    const float* __restrict__ b0a, const float* __restrict__ b0b,
    const float* __restrict__ b1, const short* __restrict__ wsplit,
    float* __restrict__ pre, float* __restrict__ qv, float* __restrict__ kv,
    float* __restrict__ vv) {
  const int wv = threadIdx.x >> 6;
  const int lane = threadIdx.x & 63;
  const int g = lane >> 4;   // A-frag k-group / D row-group
  const int c = lane & 15;   // A-frag row / D column-in-tile
  const int g0 = blockIdx.x * 16;
  const int nt0 = wv * 2;

  __shared__ __attribute__((aligned(16))) float trans[16 * 132];
  __shared__ float xs[64];
  if (threadIdx.x < 48) {
    int p = threadIdx.x / 3, cc = threadIdx.x % 3;
    xs[p * 4 + cc] = xyz[(size_t)(g0 + p) * 3 + cc];
  }
  __syncthreads();

  short8 ah[4], al[4];
  // ---- fc0a: relu(xyz @ W0a + b0a), computed directly as split A-frags ----
  {
    const float x0 = xs[c * 4 + 0], x1 = xs[c * 4 + 1], x2 = xs[c * 4 + 2];
#pragma unroll
    for (int s = 0; s < 4; ++s) {
#pragma unroll
      for (int j = 0; j < 8; ++j) {
        const int k = s * 32 + g * 8 + j;
        float v = fmaf(x2, W0a[256 + k],
                       fmaf(x1, W0a[128 + k], fmaf(x0, W0a[k], b0a[k])));
        v = fmaxf(v, 0.f);
        const short h = f2bf(v);
        ah[s][j] = h;
        al[s][j] = f2bf(v - bf2f(h));
      }
    }
  }

  floatx4 acc0, acc1;
  const floatx4 zf = (floatx4){0.f, 0.f, 0.f, 0.f};

  // ---- fc0b: pre = A @ W0b + b0b (no relu; pre stored fp32) ----
  acc0 = zf; acc1 = zf;
  split_gemm2(wsplit + 0 * 32768, nt0, lane, ah, al, acc0, acc1);
  {
    const float bb0 = b0b[nt0 * 16 + c];
    const float bb1 = b0b[(nt0 + 1) * 16 + c];
#pragma unroll
    for (int r = 0; r < 4; ++r) {
      const int row = g * 4 + r;
      float v0 = acc0[r] + bb0;
      float v1 = acc1[r] + bb1;
      pre[(size_t)(g0 + row) * 128 + nt0 * 16 + c] = v0;
      pre[(size_t)(g0 + row) * 128 + (nt0 + 1) * 16 + c] = v1;
      trans[row * 132 + nt0 * 16 + c] = v0;
      trans[row * 132 + (nt0 + 1) * 16 + c] = v1;
    }
  }
  __syncthreads();
  split_from_lds(trans, c, g, ah, al);
  __syncthreads();

  // ---- fc1: x = pre @ W1 + b1 ----
  acc0 = zf; acc1 = zf;
  split_gemm2(wsplit + 1 * 32768, nt0, lane, ah, al, acc0, acc1);
  {
    const float bb0 = b1[nt0 * 16 + c];
    const float bb1 = b1[(nt0 + 1) * 16 + c];
#pragma unroll
    for (int r = 0; r < 4; ++r) {
      const int row = g * 4 + r;
      trans[row * 132 + nt0 * 16 + c] = acc0[r] + bb0;
      trans[row * 132 + (nt0 + 1) * 16 + c] = acc1[r] + bb1;
    }
  }
  __syncthreads();
  split_from_lds(trans, c, g, ah, al);
  __syncthreads();

#define GSTORE(dst)                                                            \
  _Pragma("unroll") for (int r = 0; r < 4; ++r) {                              \
    const int row = g0 + g * 4 + r;                                            \
    dst[(size_t)row * 128 + nt0 * 16 + c] = acc0[r];                           \
    dst[(size_t)row * 128 + (nt0 + 1) * 16 + c] = acc1[r];                     \
  }

  // ---- q / k / v projections (no bias) ----
  acc0 = zf; acc1 = zf;
  split_gemm2(wsplit + 2 * 32768, nt0, lane, ah, al, acc0, acc1);
  GSTORE(qv);

  acc0 = zf; acc1 = zf;
  split_gemm2(wsplit + 3 * 32768, nt0, lane, ah, al, acc0, acc1);
  GSTORE(kv);

  acc0 = zf; acc1 = zf;
  split_gemm2(wsplit + 4 * 32768, nt0, lane, ah, al, acc0, acc1);
  GSTORE(vv);

#undef GSTORE
}

// ---------------------------------------------------------------------------
// Simple per-stage weight staging (verified, round-5 exact).
// ---------------------------------------------------------------------------
__device__ __forceinline__ void wstage(const short* __restrict__ wsw_stage,
                                       short* __restrict__ wlds, int wv,
                                       int lane) {
#pragma unroll
  for (int i = 0; i < 8; ++i) {
    short8 w_ = *reinterpret_cast<const short8*>(wsw_stage + wv * 4096 +
                                                 i * 512 + lane * 8);
    *reinterpret_cast<short8*>(&wlds[wv * 4096 + i * 512 + lane * 8]) = w_;
  }
}

// ---------------------------------------------------------------------------
// MFMA attention: round-10 verified structure (32KB wlds, 6 barriers,
// 3 blocks/CU). Round-12 change (ONLY change): vv gather hoisted to kernel
// start next to kv — its ~900cy L3/cross-XCD latency now completes under
// stages 1-2 instead of sitting on the stage-3 critical path (round-11
// showed occupancy is not the lever; the serial chain is).
// ---------------------------------------------------------------------------
__global__ __launch_bounds__(256, 3) void attn_mfma_kernel(
    const float* __restrict__ xyz, const int* __restrict__ knn,
    const float* __restrict__ qv, const float* __restrict__ kv,
    const float* __restrict__ vv, const short* __restrict__ wsw,
    const float* __restrict__ Wd1, const float* __restrict__ bd1,
    const float* __restrict__ bd2, const float* __restrict__ bg1,
    const float* __restrict__ bg2, float* __restrict__ res_ws,
    float* __restrict__ out_attn) {
  const int wv = threadIdx.x >> 6;
  const int lane = threadIdx.x & 63;
  const int g = lane >> 4;   // lane group 0..3
  const int c = lane & 15;   // column-in-tile / A-row
  const int bn = blockIdx.x * 4 + wv;
  const int b = bn >> 12;
  const int base_n = b << 12;

  __shared__ __attribute__((aligned(16))) short wlds[16384];  // 32KB: 1 stage
  __shared__ __attribute__((aligned(16))) short conv[4][16 * 136];

  // ---- neighbor indices (one 64B line per wave; L2-resident) ----
  const int* knnp = knn + (size_t)bn * 16;
  const int idxn = knnp[c];
  int idxr[4];
#pragma unroll
  for (int r = 0; r < 4; ++r) idxr[r] = knnp[g * 4 + r];

  // ---- kv AND vv prefetch into registers (both hide under stages 1-2) ----
  float kvf[8][4], vvf[8][4];
#pragma unroll
  for (int nt = 0; nt < 8; ++nt)
#pragma unroll
    for (int r = 0; r < 4; ++r) {
      kvf[nt][r] = kv[((size_t)(base_n + idxr[r])) * 128 + nt * 16 + c];
      vvf[nt][r] = vv[((size_t)(base_n + idxr[r])) * 128 + nt * 16 + c];
    }

  // ---- delta for this lane's neighbor ----
  const float ddx = xyz[(size_t)bn * 3 + 0] - xyz[((size_t)(base_n + idxn)) * 3 + 0];
  const float ddy = xyz[(size_t)bn * 3 + 1] - xyz[((size_t)(base_n + idxn)) * 3 + 1];
  const float ddz = xyz[(size_t)bn * 3 + 2] - xyz[((size_t)(base_n + idxn)) * 3 + 2];

  // ---- P1 = relu(delta @ Wd1 + bd1) directly as A-fragments ----
  short8 af[4];
#pragma unroll
  for (int s = 0; s < 4; ++s) {
#pragma unroll
    for (int j = 0; j < 8; ++j) {
      int d = s * 32 + g * 8 + j;
      float v = fmaf(ddz, Wd1[256 + d],
                     fmaf(ddy, Wd1[128 + d], fmaf(ddx, Wd1[d], bd1[d])));
      af[s][j] = f2bf(fmaxf(v, 0.f));
    }
  }

  // per-nt scalars needed in the H phase
  float qc[8], bd2v[8];
#pragma unroll
  for (int nt = 0; nt < 8; ++nt) {
    qc[nt] = qv[(size_t)bn * 128 + nt * 16 + c];
    bd2v[nt] = bd2[nt * 16 + c];
  }

  floatx4 acc[8];

// grouped ds_read + MFMA over all 8 nt tiles, B from wlds
#define STAGE_GEMM_LDS()                                                       \
  {                                                                            \
    _Pragma("unroll") for (int ks = 0; ks < 4; ++ks) {                         \
      _Pragma("unroll") for (int h2 = 0; h2 < 2; ++h2) {                       \
        short8 bfr[4];                                                         \
        _Pragma("unroll") for (int i = 0; i < 4; ++i)                          \
          bfr[i] = *reinterpret_cast<const short8*>(                           \
              &wlds[((h2 * 4 + i) * 4 + ks) * 512 + lane * 8]);                \
        _Pragma("unroll") for (int i = 0; i < 4; ++i)                          \
          acc[h2 * 4 + i] = __builtin_amdgcn_mfma_f32_16x16x32_bf16(           \
              af[ks], bfr[i], acc[h2 * 4 + i], 0, 0, 0);                       \
      }                                                                        \
    }                                                                          \
  }

  // ---- stage 1: PE = P1 @ Wd2 + bd2 ----
  wstage(wsw, wlds, wv, lane);
  __syncthreads();  // Wd2 ready
#pragma unroll
  for (int nt = 0; nt < 8; ++nt) acc[nt] = (floatx4){0.f, 0.f, 0.f, 0.f};
  STAGE_GEMM_LDS();

  // ---- H = q - kf + PE ; PE kept fp32 ; H -> LDS (bf16, C-layout) ----
  float PE[8][4];
#pragma unroll
  for (int nt = 0; nt < 8; ++nt) {
#pragma unroll
    for (int r = 0; r < 4; ++r) {
      float pe = acc[nt][r] + bd2v[nt];
      PE[nt][r] = pe;
      conv[wv][(g * 4 + r) * 136 + nt * 16 + c] =
          f2bf(qc[nt] - kvf[nt][r] + pe);
    }
  }
  LDSFENCE();
#pragma unroll
  for (int s = 0; s < 4; ++s)
    af[s] = *reinterpret_cast<const short8*>(&conv[wv][c * 136 + s * 32 + g * 8]);

  // ---- stage 2: G = relu(H @ Wg1 + bg1) ----
  __syncthreads();  // all waves done reading Wd2 from wlds
  wstage(wsw + 16384, wlds, wv, lane);
  __syncthreads();  // Wg1 ready
#pragma unroll
  for (int nt = 0; nt < 8; ++nt) acc[nt] = (floatx4){0.f, 0.f, 0.f, 0.f};
  STAGE_GEMM_LDS();
#pragma unroll
  for (int nt = 0; nt < 8; ++nt) {
    const float bg1v = bg1[nt * 16 + c];
#pragma unroll
    for (int r = 0; r < 4; ++r) {
      conv[wv][(g * 4 + r) * 136 + nt * 16 + c] =
          f2bf(fmaxf(acc[nt][r] + bg1v, 0.f));
    }
  }
  LDSFENCE();
#pragma unroll
  for (int s = 0; s < 4; ++s)
    af[s] = *reinterpret_cast<const short8*>(&conv[wv][c * 136 + s * 32 + g * 8]);

  // ---- stage 3: logits = G @ Wg2 + bg2, two 4-nt halves + softmax ----
  __syncthreads();  // all waves done reading Wg1
  wstage(wsw + 32768, wlds, wv, lane);
  __syncthreads();  // Wg2 ready

  const float inv = 0.0883883476483184f;  // 1/sqrt(128)
  float resv[8];
#pragma unroll
  for (int h = 0; h < 2; ++h) {
    const int ntb = h * 4;

    floatx4 acch[4];
#pragma unroll
    for (int i = 0; i < 4; ++i) acch[i] = (floatx4){0.f, 0.f, 0.f, 0.f};
#pragma unroll
    for (int ks = 0; ks < 4; ++ks) {
      short8 bfr[4];
#pragma unroll
      for (int i = 0; i < 4; ++i)
        bfr[i] = *reinterpret_cast<const short8*>(
            &wlds[((ntb + i) * 4 + ks) * 512 + lane * 8]);
#pragma unroll
      for (int i = 0; i < 4; ++i)
        acch[i] = __builtin_amdgcn_mfma_f32_16x16x32_bf16(af[ks], bfr[i],
                                                          acch[i], 0, 0, 0);
    }

#pragma unroll
    for (int i = 0; i < 4; ++i) {
      const int nt = ntb + i;
      const float bg2v = bg2[nt * 16 + c];
      float l0 = (acch[i][0] + bg2v) * inv;
      float l1 = (acch[i][1] + bg2v) * inv;
      float l2 = (acch[i][2] + bg2v) * inv;
      float l3 = (acch[i][3] + bg2v) * inv;
      float m4 = fmaxf(fmaxf(l0, l1), fmaxf(l2, l3));
      m4 = fmaxf(m4, __shfl_xor(m4, 16));
      m4 = fmaxf(m4, __shfl_xor(m4, 32));
      float e0 = __expf(l0 - m4), e1 = __expf(l1 - m4);
      float e2 = __expf(l2 - m4), e3 = __expf(l3 - m4);
      float s4 = e0 + e1 + e2 + e3;
      s4 += __shfl_xor(s4, 16);
      s4 += __shfl_xor(s4, 32);
      float rs = 1.f / s4;
      float a0 = e0 * rs, a1 = e1 * rs, a2 = e2 * rs, a3 = e3 * rs;
      size_t base = ((size_t)bn * 16 + g * 4) * 128 + nt * 16 + c;
      out_attn[base + 0 * 128] = a0;
      out_attn[base + 1 * 128] = a1;
      out_attn[base + 2 * 128] = a2;
      out_attn[base + 3 * 128] = a3;
      float r = 0.f;
      r = fmaf(a0, vvf[nt][0] + PE[nt][0], r);
      r = fmaf(a1, vvf[nt][1] + PE[nt][1], r);
      r = fmaf(a2, vvf[nt][2] + PE[nt][2], r);
      r = fmaf(a3, vvf[nt][3] + PE[nt][3], r);
      r += __shfl_xor(r, 16);
      r += __shfl_xor(r, 32);
      resv[nt] = r;
    }
  }
#undef STAGE_GEMM_LDS

  if (g == 0) {
#pragma unroll
    for (int nt = 0; nt < 8; ++nt)
      res_ws[(size_t)bn * 128 + nt * 16 + c] = resv[nt];
  }
}

// ---------------------------------------------------------------------------
// Epilogue on matrix cores (verified, round-5 exact).
// ---------------------------------------------------------------------------
__global__ __launch_bounds__(256, 4) void epilogue_mfma_kernel(
    const float* __restrict__ res_ws, const short* __restrict__ wsplit,
    const float* __restrict__ b2, const float* __restrict__ pre,
    float* __restrict__ out_res) {
  const int wv = threadIdx.x >> 6;
  const int lane = threadIdx.x & 63;
  const int g = lane >> 4;
  const int c = lane & 15;
  const int g0 = blockIdx.x * 16;
  const int nt0 = wv * 2;

  __shared__ __attribute__((aligned(16))) float trans[16 * 132];

#pragma unroll
  for (int i = 0; i < 2; ++i) {
    int idx4 = threadIdx.x + i * 256;  // 0..511 float4s
    int row = idx4 >> 5;
    int col4 = idx4 & 31;
    float4 v = *reinterpret_cast<const float4*>(
        res_ws + (size_t)(g0 + row) * 128 + col4 * 4);
    *reinterpret_cast<float4*>(&trans[row * 132 + col4 * 4]) = v;
  }
  __syncthreads();

  short8 ah[4], al[4];
  split_from_lds(trans, c, g, ah, al);

  float prv0[4], prv1[4];
  const float bb0 = b2[nt0 * 16 + c];
  const float bb1 = b2[(nt0 + 1) * 16 + c];
#pragma unroll
  for (int r = 0; r < 4; ++r) {
    prv0[r] = pre[(size_t)(g0 + g * 4 + r) * 128 + nt0 * 16 + c];
    prv1[r] = pre[(size_t)(g0 + g * 4 + r) * 128 + (nt0 + 1) * 16 + c];
  }

  floatx4 acc0 = (floatx4){0.f, 0.f, 0.f, 0.f};
  floatx4 acc1 = (floatx4){0.f, 0.f, 0.f, 0.f};
  split_gemm2(wsplit + 5 * 32768, nt0, lane, ah, al, acc0, acc1);

#pragma unroll
  for (int r = 0; r < 4; ++r) {
    const int row = g0 + g * 4 + r;
    out_res[(size_t)row * 128 + nt0 * 16 + c] = acc0[r] + bb0 + prv0[r];
    out_res[(size_t)row * 128 + (nt0 + 1) * 16 + c] = acc1[r] + bb1 + prv1[r];
  }
}

extern "C" void kernel_launch(void* const* d_in, const int* in_sizes, int n_in,
                              void* d_out, int out_size, void* d_ws,
                              size_t ws_size, hipStream_t stream) {
  const float* xyz = (const float*)d_in[0];
  const float* W0a = (const float*)d_in[1];
  const float* b0a = (const float*)d_in[2];
  const float* W0b = (const float*)d_in[3];
  const float* b0b = (const float*)d_in[4];
  const float* W1 = (const float*)d_in[5];
  const float* b1 = (const float*)d_in[6];
  const float* W2 = (const float*)d_in[7];
  const float* b2 = (const float*)d_in[8];
  const float* Wd1 = (const float*)d_in[9];
  const float* bd1 = (const float*)d_in[10];
  const float* Wd2 = (const float*)d_in[11];
  const float* bd2 = (const float*)d_in[12];
  const float* Wg1 = (const float*)d_in[13];
  const float* bg1 = (const float*)d_in[14];
  const float* Wg2 = (const float*)d_in[15];
  const float* bg2 = (const float*)d_in[16];
  const float* Wq = (const float*)d_in[17];
  const float* Wk = (const float*)d_in[18];
  const float* Wv = (const float*)d_in[19];

  char* ws = (char*)d_ws;
  int* knn = (int*)ws;                                  // 1 MB
  float* pre = (float*)(ws + (1 << 20));                // 8 MB
  float* qv = (float*)(ws + (9 << 20));                 // 8 MB
  float* kv = (float*)(ws + (17 << 20));                // 8 MB
  float* vv = (float*)(ws + (25 << 20));                // 8 MB
  float* res_ws = (float*)(ws + (33 << 20));            // 8 MB
  short* wsw = (short*)(ws + (41 << 20));               // 96 KB bf16 B-frags
  short* wsplit = (short*)(ws + (41 << 20) + (128 << 10));  // 384 KB split frags
  float4* pts4 = (float4*)(ws + (42 << 20));            // 256 KB packed points

  float* out_res = (float*)d_out;
  float* out_attn = out_res + (size_t)BN * DD;

  hipLaunchKernelGGL(swz_all_kernel, dim3(72), dim3(256), 0, stream, xyz, Wd2,
                     Wg1, Wg2, W0b, W1, Wq, Wk, Wv, W2, wsw, wsplit, pts4);
  hipLaunchKernelGGL(knn_kernel, dim3(1024), dim3(256), 0, stream, pts4, knn);
  hipLaunchKernelGGL(point_mlp_mfma_kernel, dim3(1024), dim3(256), 0, stream,
                     xyz, W0a, b0a, b0b, b1, wsplit, pre, qv, kv, vv);
  hipLaunchKernelGGL(attn_mfma_kernel, dim3(4096), dim3(256), 0, stream, xyz,
                     knn, qv, kv, vv, wsw, Wd1, bd1, bd2, bg1, bg2, res_ws,
                     out_attn);
  hipLaunchKernelGGL(epilogue_mfma_kernel, dim3(1024), dim3(256), 0, stream,
                     res_ws, wsplit, b2, pre, out_res);
}

// Round 13
// 329.603 us; speedup vs baseline: 1.1423x; 1.1423x over previous
//
#include <hip/hip_runtime.h>
#include <math.h>

#define BB 4
#define NN 4096
#define KNNK 16
#define DD 128
#define BN (BB*NN)

typedef __attribute__((ext_vector_type(8))) short short8;   // 8 bf16
typedef __attribute__((ext_vector_type(4))) float floatx4;  // MFMA acc

// Compiler-native bf16 convert (RNE; verified round 10).
__device__ __forceinline__ short f2bf(float x) {
  __bf16 b = (__bf16)x;
  return (short)__builtin_bit_cast(unsigned short, b);
}

__device__ __forceinline__ float bf2f(short h) {
  return __uint_as_float((unsigned)(unsigned short)h << 16);
}

// Per-wave LDS fence (conv[] is wave-private; verified round 3/5/7).
#define LDSFENCE() asm volatile("s_waitcnt lgkmcnt(0)" ::: "memory")

// ---------------------------------------------------------------------------
// Shared split-bf16 GEMM helpers (verified structure).
// ---------------------------------------------------------------------------
__device__ __forceinline__ void split_from_lds(const float* __restrict__ trans,
                                               int c, int g, short8 ah[4],
                                               short8 al[4]) {
#pragma unroll
  for (int s = 0; s < 4; ++s) {
    const float* p_ = &trans[c * 132 + s * 32 + g * 8];
    float4 u0 = *reinterpret_cast<const float4*>(p_);
    float4 u1 = *reinterpret_cast<const float4*>(p_ + 4);
    float tmp[8] = {u0.x, u0.y, u0.z, u0.w, u1.x, u1.y, u1.z, u1.w};
#pragma unroll
    for (int j = 0; j < 8; ++j) {
      short h_ = f2bf(tmp[j]);
      ah[s][j] = h_;
      al[s][j] = f2bf(tmp[j] - bf2f(h_));
    }
  }
}

__device__ __forceinline__ void split_gemm2(const short* __restrict__ Bh,
                                            int nt0, int lane,
                                            const short8 ah[4],
                                            const short8 al[4], floatx4& acc0,
                                            floatx4& acc1) {
  const short* Bl = Bh + 16384;
#pragma unroll
  for (int ks = 0; ks < 4; ++ks) {
    const size_t o0 = ((size_t)((nt0 + 0) * 4 + ks) * 64 + lane) * 8;
    const size_t o1 = ((size_t)((nt0 + 1) * 4 + ks) * 64 + lane) * 8;
    short8 bh0 = *reinterpret_cast<const short8*>(Bh + o0);
    short8 bl0 = *reinterpret_cast<const short8*>(Bl + o0);
    short8 bh1 = *reinterpret_cast<const short8*>(Bh + o1);
    short8 bl1 = *reinterpret_cast<const short8*>(Bl + o1);
    acc0 = __builtin_amdgcn_mfma_f32_16x16x32_bf16(ah[ks], bh0, acc0, 0, 0, 0);
    acc1 = __builtin_amdgcn_mfma_f32_16x16x32_bf16(ah[ks], bh1, acc1, 0, 0, 0);
    acc0 = __builtin_amdgcn_mfma_f32_16x16x32_bf16(ah[ks], bl0, acc0, 0, 0, 0);
    acc1 = __builtin_amdgcn_mfma_f32_16x16x32_bf16(ah[ks], bl1, acc1, 0, 0, 0);
    acc0 = __builtin_amdgcn_mfma_f32_16x16x32_bf16(al[ks], bh0, acc0, 0, 0, 0);
    acc1 = __builtin_amdgcn_mfma_f32_16x16x32_bf16(al[ks], bh1, acc1, 0, 0, 0);
  }
}

// ---------------------------------------------------------------------------
// KNN v6 (verified round 10): 4 queries/wave, float4 pts4 loads.
// Standalone kernel — round-8 fusion regressed 2x; do not re-fuse.
// ---------------------------------------------------------------------------
__device__ __forceinline__ void ced(double& a, double& b) {
  double mn = fmin(a, b);
  double mx = fmax(a, b);
  a = mn;
  b = mx;
}

__device__ __forceinline__ void dsort16(double v[16]) {
#define CE(i, j) ced(v[i], v[j]);
  CE(0, 1) CE(2, 3) CE(4, 5) CE(6, 7) CE(8, 9) CE(10, 11) CE(12, 13) CE(14, 15)
  CE(0, 2) CE(1, 3) CE(4, 6) CE(5, 7) CE(8, 10) CE(9, 11) CE(12, 14) CE(13, 15)
  CE(1, 2) CE(5, 6) CE(9, 10) CE(13, 14)
  CE(0, 4) CE(1, 5) CE(2, 6) CE(3, 7) CE(8, 12) CE(9, 13) CE(10, 14) CE(11, 15)
  CE(2, 4) CE(3, 5) CE(10, 12) CE(11, 13)
  CE(1, 2) CE(3, 4) CE(5, 6) CE(9, 10) CE(11, 12) CE(13, 14)
  CE(0, 8) CE(1, 9) CE(2, 10) CE(3, 11) CE(4, 12) CE(5, 13) CE(6, 14) CE(7, 15)
  CE(4, 8) CE(5, 9) CE(6, 10) CE(7, 11)
  CE(2, 4) CE(3, 5) CE(6, 8) CE(7, 9) CE(10, 12) CE(11, 13)
  CE(1, 2) CE(3, 4) CE(5, 6) CE(7, 8) CE(9, 10) CE(11, 12) CE(13, 14)
#undef CE
}

// sort a 16-element bitonic sequence ascending
__device__ __forceinline__ void dbitonic16(double m[16]) {
#pragma unroll
  for (int s = 8; s >= 1; s >>= 1) {
#pragma unroll
    for (int i = 0; i < 16; ++i) {
      if ((i & s) == 0) ced(m[i], m[i + s]);
    }
  }
}

__global__ __launch_bounds__(256, 4) void knn_kernel(
    const float4* __restrict__ pts4, int* __restrict__ knn) {
  const int wv = threadIdx.x >> 6;
  const int lane = threadIdx.x & 63;
  const int ln = lane & 15;   // lane within 16-lane query group
  const int qg = lane >> 4;   // query group 0..3 within wave
  const int q = blockIdx.x * 16 + wv * 4 + qg;
  const int b = q >> 12;
  const int n = q & 4095;
  const float4* pb = pts4 + ((size_t)b << 12);

  const float4 qp = pb[n];
  const float qx = qp.x, qy = qp.y, qz = qp.z, qsq = qp.w;

#define LOADBATCH(batch)                                                       \
  _Pragma("unroll") for (int i = 0; i < 16; ++i) {                             \
    const int c = ((batch) * 16 + i) * 16 + ln;                                \
    float4 p = pb[c];                                                          \
    float dot = __fadd_rn(__fadd_rn(__fmul_rn(qx, p.x), __fmul_rn(qy, p.y)),   \
                          __fmul_rn(qz, p.z));                                 \
    float d = __fadd_rn(__fsub_rn(qsq, __fmul_rn(2.0f, dot)), p.w);            \
    unsigned u = __float_as_uint(d);                                           \
    u = (u & 0x80000000u) ? ~u : (u | 0x80000000u);                            \
    unsigned long long key =                                                   \
        0x3FF0000000000000ULL | (((unsigned long long)u << 12) | (unsigned)c); \
    v[i] = __longlong_as_double((long long)key);                               \
  }

  double top[16];
  {
    double v[16];
    LOADBATCH(0);
    dsort16(v);
#pragma unroll
    for (int i = 0; i < 16; ++i) top[i] = v[i];
  }
#pragma unroll 1
  for (int batch = 1; batch < 16; ++batch) {
    double v[16];
    LOADBATCH(batch);
    dsort16(v);
    double m[16];
#pragma unroll
    for (int i = 0; i < 16; ++i)
      m[i] = fmin(top[i], v[15 - i]);  // min(asc, desc) -> bitonic lower half
    dbitonic16(m);
#pragma unroll
    for (int i = 0; i < 16; ++i) top[i] = m[i];
  }
#undef LOADBATCH

  // cross-lane merge within the 16-lane query group (masks 1,2,4,8)
#pragma unroll
  for (int mask = 1; mask <= 8; mask <<= 1) {
    double oth[16];
#pragma unroll
    for (int i = 0; i < 16; ++i) {
      double y = __shfl_xor(top[15 - i], mask);
      oth[i] = fmin(y, top[i]);
    }
    dbitonic16(oth);
#pragma unroll
    for (int i = 0; i < 16; ++i) top[i] = oth[i];
  }

  if (ln == 0) {
    int* outp = knn + (size_t)q * KNNK;
#pragma unroll
    for (int k = 0; k < 16; ++k)
      outp[k] = (int)(__double_as_longlong(top[k]) & 0xFFFLL);
  }
}

// ---------------------------------------------------------------------------
// Combined weight pre-swizzle + pts4 precompute (verified, round-10 exact).
// ---------------------------------------------------------------------------
__global__ void swz_all_kernel(const float* __restrict__ xyz,
                               const float* __restrict__ Wd2,
                               const float* __restrict__ Wg1,
                               const float* __restrict__ Wg2,
                               const float* __restrict__ W0b,
                               const float* __restrict__ W1,
                               const float* __restrict__ Wq,
                               const float* __restrict__ Wk,
                               const float* __restrict__ Wv,
                               const float* __restrict__ W2,
                               short* __restrict__ wsw,
                               short* __restrict__ wsplit,
                               float4* __restrict__ pts4) {
  int t = blockIdx.x * 256 + threadIdx.x;
  if (t < BN) {
    float cx = xyz[(size_t)t * 3 + 0];
    float cy = xyz[(size_t)t * 3 + 1];
    float cz = xyz[(size_t)t * 3 + 2];
    float csq = __fadd_rn(__fadd_rn(__fmul_rn(cx, cx), __fmul_rn(cy, cy)),
                          __fmul_rn(cz, cz));
    pts4[t] = make_float4(cx, cy, cz, csq);
  }
  if (t < 3 * 2048) {
    int stage = t / 2048;
    int rem = t % 2048;
    int nt = rem / 256;
    int ks = (rem % 256) / 64;
    int lane = rem % 64;
    const float* W = (stage == 0) ? Wd2 : (stage == 1) ? Wg1 : Wg2;
    short8 o;
#pragma unroll
    for (int j = 0; j < 8; ++j) {
      int k = ks * 32 + (lane >> 4) * 8 + j;
      int n = nt * 16 + (lane & 15);
      o[j] = f2bf(W[k * 128 + n]);
    }
    *reinterpret_cast<short8*>(wsw + (size_t)t * 8) = o;
  } else {
    int u = t - 3 * 2048;
    if (u >= 6 * 2048) return;
    int mat = u / 2048;
    int rem = u % 2048;
    int nt = rem / 256;
    int ks = (rem % 256) / 64;
    int lane = rem % 64;
    const float* W = (mat == 0) ? W0b : (mat == 1) ? W1 : (mat == 2) ? Wq
                     : (mat == 3) ? Wk : (mat == 4) ? Wv : W2;
    short8 hi, lo;
#pragma unroll
    for (int j = 0; j < 8; ++j) {
      int k = ks * 32 + (lane >> 4) * 8 + j;
      int n = nt * 16 + (lane & 15);
      float w = W[k * 128 + n];
      short h = f2bf(w);
      hi[j] = h;
      lo[j] = f2bf(w - bf2f(h));
    }
    *reinterpret_cast<short8*>(wsplit + ((size_t)(2 * mat) * 2048 + rem) * 8) = hi;
    *reinterpret_cast<short8*>(wsplit + ((size_t)(2 * mat + 1) * 2048 + rem) * 8) = lo;
  }
}

// ---------------------------------------------------------------------------
// Point-MLP on matrix cores (verified, round-5/7/9/10 exact).
// ---------------------------------------------------------------------------
__global__ __launch_bounds__(256, 4) void point_mlp_mfma_kernel(
    const float* __restrict__ xyz, const float* __restrict__ W0a,
    const float* __restrict__ b0a, const float* __restrict__ b0b,
    const float* __restrict__ b1, const short* __restrict__ wsplit,
    float* __restrict__ pre, float* __restrict__ qv, float* __restrict__ kv,
    float* __restrict__ vv) {
  const int wv = threadIdx.x >> 6;
  const int lane = threadIdx.x & 63;
  const int g = lane >> 4;   // A-frag k-group / D row-group
  const int c = lane & 15;   // A-frag row / D column-in-tile
  const int g0 = blockIdx.x * 16;
  const int nt0 = wv * 2;

  __shared__ __attribute__((aligned(16))) float trans[16 * 132];
  __shared__ float xs[64];
  if (threadIdx.x < 48) {
    int p = threadIdx.x / 3, cc = threadIdx.x % 3;
    xs[p * 4 + cc] = xyz[(size_t)(g0 + p) * 3 + cc];
  }
  __syncthreads();

  short8 ah[4], al[4];
  // ---- fc0a: relu(xyz @ W0a + b0a), computed directly as split A-frags ----
  {
    const float x0 = xs[c * 4 + 0], x1 = xs[c * 4 + 1], x2 = xs[c * 4 + 2];
#pragma unroll
    for (int s = 0; s < 4; ++s) {
#pragma unroll
      for (int j = 0; j < 8; ++j) {
        const int k = s * 32 + g * 8 + j;
        float v = fmaf(x2, W0a[256 + k],
                       fmaf(x1, W0a[128 + k], fmaf(x0, W0a[k], b0a[k])));
        v = fmaxf(v, 0.f);
        const short h = f2bf(v);
        ah[s][j] = h;
        al[s][j] = f2bf(v - bf2f(h));
      }
    }
  }

  floatx4 acc0, acc1;
  const floatx4 zf = (floatx4){0.f, 0.f, 0.f, 0.f};

  // ---- fc0b: pre = A @ W0b + b0b (no relu; pre stored fp32) ----
  acc0 = zf; acc1 = zf;
  split_gemm2(wsplit + 0 * 32768, nt0, lane, ah, al, acc0, acc1);
  {
    const float bb0 = b0b[nt0 * 16 + c];
    const float bb1 = b0b[(nt0 + 1) * 16 + c];
#pragma unroll
    for (int r = 0; r < 4; ++r) {
      const int row = g * 4 + r;
      float v0 = acc0[r] + bb0;
      float v1 = acc1[r] + bb1;
      pre[(size_t)(g0 + row) * 128 + nt0 * 16 + c] = v0;
      pre[(size_t)(g0 + row) * 128 + (nt0 + 1) * 16 + c] = v1;
      trans[row * 132 + nt0 * 16 + c] = v0;
      trans[row * 132 + (nt0 + 1) * 16 + c] = v1;
    }
  }
  __syncthreads();
  split_from_lds(trans, c, g, ah, al);
  __syncthreads();

  // ---- fc1: x = pre @ W1 + b1 ----
  acc0 = zf; acc1 = zf;
  split_gemm2(wsplit + 1 * 32768, nt0, lane, ah, al, acc0, acc1);
  {
    const float bb0 = b1[nt0 * 16 + c];
    const float bb1 = b1[(nt0 + 1) * 16 + c];
#pragma unroll
    for (int r = 0; r < 4; ++r) {
      const int row = g * 4 + r;
      trans[row * 132 + nt0 * 16 + c] = acc0[r] + bb0;
      trans[row * 132 + (nt0 + 1) * 16 + c] = acc1[r] + bb1;
    }
  }
  __syncthreads();
  split_from_lds(trans, c, g, ah, al);
  __syncthreads();

#define GSTORE(dst)                                                            \
  _Pragma("unroll") for (int r = 0; r < 4; ++r) {                              \
    const int row = g0 + g * 4 + r;                                            \
    dst[(size_t)row * 128 + nt0 * 16 + c] = acc0[r];                           \
    dst[(size_t)row * 128 + (nt0 + 1) * 16 + c] = acc1[r];                     \
  }

  // ---- q / k / v projections (no bias) ----
  acc0 = zf; acc1 = zf;
  split_gemm2(wsplit + 2 * 32768, nt0, lane, ah, al, acc0, acc1);
  GSTORE(qv);

  acc0 = zf; acc1 = zf;
  split_gemm2(wsplit + 3 * 32768, nt0, lane, ah, al, acc0, acc1);
  GSTORE(kv);

  acc0 = zf; acc1 = zf;
  split_gemm2(wsplit + 4 * 32768, nt0, lane, ah, al, acc0, acc1);
  GSTORE(vv);

#undef GSTORE
}

// ---------------------------------------------------------------------------
// Simple per-stage weight staging (verified, round-5 exact).
// ---------------------------------------------------------------------------
__device__ __forceinline__ void wstage(const short* __restrict__ wsw_stage,
                                       short* __restrict__ wlds, int wv,
                                       int lane) {
#pragma unroll
  for (int i = 0; i < 8; ++i) {
    short8 w_ = *reinterpret_cast<const short8*>(wsw_stage + wv * 4096 +
                                                 i * 512 + lane * 8);
    *reinterpret_cast<short8*>(&wlds[wv * 4096 + i * 512 + lane * 8]) = w_;
  }
}

// ---------------------------------------------------------------------------
// MFMA attention (round-10 verified best: 32KB wlds, 6 barriers, 3 blocks/CU,
// __expf, per-half vv gather inside stage 3). Round-12's vv hoist regressed
// (VGPR lifetime across all stages -> allocator sank/serialized the loads;
// 93 -> 136 us). Reverted byte-identical to round-10.
// ---------------------------------------------------------------------------
__global__ __launch_bounds__(256, 3) void attn_mfma_kernel(
    const float* __restrict__ xyz, const int* __restrict__ knn,
    const float* __restrict__ qv, const float* __restrict__ kv,
    const float* __restrict__ vv, const short* __restrict__ wsw,
    const float* __restrict__ Wd1, const float* __restrict__ bd1,
    const float* __restrict__ bd2, const float* __restrict__ bg1,
    const float* __restrict__ bg2, float* __restrict__ res_ws,
    float* __restrict__ out_attn) {
  const int wv = threadIdx.x >> 6;
  const int lane = threadIdx.x & 63;
  const int g = lane >> 4;   // lane group 0..3
  const int c = lane & 15;   // column-in-tile / A-row
  const int bn = blockIdx.x * 4 + wv;
  const int b = bn >> 12;
  const int base_n = b << 12;

  __shared__ __attribute__((aligned(16))) short wlds[16384];  // 32KB: 1 stage
  __shared__ __attribute__((aligned(16))) short conv[4][16 * 136];

  // ---- neighbor indices (one 64B line per wave; L2-resident) ----
  const int* knnp = knn + (size_t)bn * 16;
  const int idxn = knnp[c];
  int idxr[4];
#pragma unroll
  for (int r = 0; r < 4; ++r) idxr[r] = knnp[g * 4 + r];

  // ---- kv prefetch into registers ----
  float kvf[8][4];
#pragma unroll
  for (int nt = 0; nt < 8; ++nt)
#pragma unroll
    for (int r = 0; r < 4; ++r)
      kvf[nt][r] = kv[((size_t)(base_n + idxr[r])) * 128 + nt * 16 + c];

  // ---- delta for this lane's neighbor ----
  const float ddx = xyz[(size_t)bn * 3 + 0] - xyz[((size_t)(base_n + idxn)) * 3 + 0];
  const float ddy = xyz[(size_t)bn * 3 + 1] - xyz[((size_t)(base_n + idxn)) * 3 + 1];
  const float ddz = xyz[(size_t)bn * 3 + 2] - xyz[((size_t)(base_n + idxn)) * 3 + 2];

  // ---- P1 = relu(delta @ Wd1 + bd1) directly as A-fragments ----
  short8 af[4];
#pragma unroll
  for (int s = 0; s < 4; ++s) {
#pragma unroll
    for (int j = 0; j < 8; ++j) {
      int d = s * 32 + g * 8 + j;
      float v = fmaf(ddz, Wd1[256 + d],
                     fmaf(ddy, Wd1[128 + d], fmaf(ddx, Wd1[d], bd1[d])));
      af[s][j] = f2bf(fmaxf(v, 0.f));
    }
  }

  // per-nt scalars needed in the H phase
  float qc[8], bd2v[8];
#pragma unroll
  for (int nt = 0; nt < 8; ++nt) {
    qc[nt] = qv[(size_t)bn * 128 + nt * 16 + c];
    bd2v[nt] = bd2[nt * 16 + c];
  }

  floatx4 acc[8];

// grouped ds_read + MFMA over all 8 nt tiles, B from wlds
#define STAGE_GEMM_LDS()                                                       \
  {                                                                            \
    _Pragma("unroll") for (int ks = 0; ks < 4; ++ks) {                         \
      _Pragma("unroll") for (int h2 = 0; h2 < 2; ++h2) {                       \
        short8 bfr[4];                                                         \
        _Pragma("unroll") for (int i = 0; i < 4; ++i)                          \
          bfr[i] = *reinterpret_cast<const short8*>(                           \
              &wlds[((h2 * 4 + i) * 4 + ks) * 512 + lane * 8]);                \
        _Pragma("unroll") for (int i = 0; i < 4; ++i)                          \
          acc[h2 * 4 + i] = __builtin_amdgcn_mfma_f32_16x16x32_bf16(           \
              af[ks], bfr[i], acc[h2 * 4 + i], 0, 0, 0);                       \
      }                                                                        \
    }                                                                          \
  }

  // ---- stage 1: PE = P1 @ Wd2 + bd2 ----
  wstage(wsw, wlds, wv, lane);
  __syncthreads();  // Wd2 ready
#pragma unroll
  for (int nt = 0; nt < 8; ++nt) acc[nt] = (floatx4){0.f, 0.f, 0.f, 0.f};
  STAGE_GEMM_LDS();

  // ---- H = q - kf + PE ; PE kept fp32 ; H -> LDS (bf16, C-layout) ----
  float PE[8][4];
#pragma unroll
  for (int nt = 0; nt < 8; ++nt) {
#pragma unroll
    for (int r = 0; r < 4; ++r) {
      float pe = acc[nt][r] + bd2v[nt];
      PE[nt][r] = pe;
      conv[wv][(g * 4 + r) * 136 + nt * 16 + c] =
          f2bf(qc[nt] - kvf[nt][r] + pe);
    }
  }
  LDSFENCE();
#pragma unroll
  for (int s = 0; s < 4; ++s)
    af[s] = *reinterpret_cast<const short8*>(&conv[wv][c * 136 + s * 32 + g * 8]);

  // ---- stage 2: G = relu(H @ Wg1 + bg1) ----
  __syncthreads();  // all waves done reading Wd2 from wlds
  wstage(wsw + 16384, wlds, wv, lane);
  __syncthreads();  // Wg1 ready
#pragma unroll
  for (int nt = 0; nt < 8; ++nt) acc[nt] = (floatx4){0.f, 0.f, 0.f, 0.f};
  STAGE_GEMM_LDS();
#pragma unroll
  for (int nt = 0; nt < 8; ++nt) {
    const float bg1v = bg1[nt * 16 + c];
#pragma unroll
    for (int r = 0; r < 4; ++r) {
      conv[wv][(g * 4 + r) * 136 + nt * 16 + c] =
          f2bf(fmaxf(acc[nt][r] + bg1v, 0.f));
    }
  }
  LDSFENCE();
#pragma unroll
  for (int s = 0; s < 4; ++s)
    af[s] = *reinterpret_cast<const short8*>(&conv[wv][c * 136 + s * 32 + g * 8]);

  // ---- stage 3: logits = G @ Wg2 + bg2, two 4-nt halves + softmax ----
  __syncthreads();  // all waves done reading Wg1
  wstage(wsw + 32768, wlds, wv, lane);
  __syncthreads();  // Wg2 ready

  const float inv = 0.0883883476483184f;  // 1/sqrt(128)
  float resv[8];
#pragma unroll
  for (int h = 0; h < 2; ++h) {
    const int ntb = h * 4;
    float vvf[4][4];
#pragma unroll
    for (int i = 0; i < 4; ++i)
#pragma unroll
      for (int r = 0; r < 4; ++r)
        vvf[i][r] =
            vv[((size_t)(base_n + idxr[r])) * 128 + (ntb + i) * 16 + c];

    floatx4 acch[4];
#pragma unroll
    for (int i = 0; i < 4; ++i) acch[i] = (floatx4){0.f, 0.f, 0.f, 0.f};
#pragma unroll
    for (int ks = 0; ks < 4; ++ks) {
      short8 bfr[4];
#pragma unroll
      for (int i = 0; i < 4; ++i)
        bfr[i] = *reinterpret_cast<const short8*>(
            &wlds[((ntb + i) * 4 + ks) * 512 + lane * 8]);
#pragma unroll
      for (int i = 0; i < 4; ++i)
        acch[i] = __builtin_amdgcn_mfma_f32_16x16x32_bf16(af[ks], bfr[i],
                                                          acch[i], 0, 0, 0);
    }

#pragma unroll
    for (int i = 0; i < 4; ++i) {
      const int nt = ntb + i;
      const float bg2v = bg2[nt * 16 + c];
      float l0 = (acch[i][0] + bg2v) * inv;
      float l1 = (acch[i][1] + bg2v) * inv;
      float l2 = (acch[i][2] + bg2v) * inv;
      float l3 = (acch[i][3] + bg2v) * inv;
      float m4 = fmaxf(fmaxf(l0, l1), fmaxf(l2, l3));
      m4 = fmaxf(m4, __shfl_xor(m4, 16));
      m4 = fmaxf(m4, __shfl_xor(m4, 32));
      float e0 = __expf(l0 - m4), e1 = __expf(l1 - m4);
      float e2 = __expf(l2 - m4), e3 = __expf(l3 - m4);
      float s4 = e0 + e1 + e2 + e3;
      s4 += __shfl_xor(s4, 16);
      s4 += __shfl_xor(s4, 32);
      float rs = 1.f / s4;
      float a0 = e0 * rs, a1 = e1 * rs, a2 = e2 * rs, a3 = e3 * rs;
      size_t base = ((size_t)bn * 16 + g * 4) * 128 + nt * 16 + c;
      out_attn[base + 0 * 128] = a0;
      out_attn[base + 1 * 128] = a1;
      out_attn[base + 2 * 128] = a2;
      out_attn[base + 3 * 128] = a3;
      float r = 0.f;
      r = fmaf(a0, vvf[i][0] + PE[nt][0], r);
      r = fmaf(a1, vvf[i][1] + PE[nt][1], r);
      r = fmaf(a2, vvf[i][2] + PE[nt][2], r);
      r = fmaf(a3, vvf[i][3] + PE[nt][3], r);
      r += __shfl_xor(r, 16);
      r += __shfl_xor(r, 32);
      resv[nt] = r;
    }
  }
#undef STAGE_GEMM_LDS

  if (g == 0) {
#pragma unroll
    for (int nt = 0; nt < 8; ++nt)
      res_ws[(size_t)bn * 128 + nt * 16 + c] = resv[nt];
  }
}

// ---------------------------------------------------------------------------
// Epilogue on matrix cores (verified, round-5 exact).
// ---------------------------------------------------------------------------
__global__ __launch_bounds__(256, 4) void epilogue_mfma_kernel(
    const float* __restrict__ res_ws, const short* __restrict__ wsplit,
    const float* __restrict__ b2, const float* __restrict__ pre,
    float* __restrict__ out_res) {
  const int wv = threadIdx.x >> 6;
  const int lane = threadIdx.x & 63;
  const int g = lane >> 4;
  const int c = lane & 15;
  const int g0 = blockIdx.x * 16;
  const int nt0 = wv * 2;

  __shared__ __attribute__((aligned(16))) float trans[16 * 132];

#pragma unroll
  for (int i = 0; i < 2; ++i) {
    int idx4 = threadIdx.x + i * 256;  // 0..511 float4s
    int row = idx4 >> 5;
    int col4 = idx4 & 31;
    float4 v = *reinterpret_cast<const float4*>(
        res_ws + (size_t)(g0 + row) * 128 + col4 * 4);
    *reinterpret_cast<float4*>(&trans[row * 132 + col4 * 4]) = v;
  }
  __syncthreads();

  short8 ah[4], al[4];
  split_from_lds(trans, c, g, ah, al);

  float prv0[4], prv1[4];
  const float bb0 = b2[nt0 * 16 + c];
  const float bb1 = b2[(nt0 + 1) * 16 + c];
#pragma unroll
  for (int r = 0; r < 4; ++r) {
    prv0[r] = pre[(size_t)(g0 + g * 4 + r) * 128 + nt0 * 16 + c];
    prv1[r] = pre[(size_t)(g0 + g * 4 + r) * 128 + (nt0 + 1) * 16 + c];
  }

  floatx4 acc0 = (floatx4){0.f, 0.f, 0.f, 0.f};
  floatx4 acc1 = (floatx4){0.f, 0.f, 0.f, 0.f};
  split_gemm2(wsplit + 5 * 32768, nt0, lane, ah, al, acc0, acc1);

#pragma unroll
  for (int r = 0; r < 4; ++r) {
    const int row = g0 + g * 4 + r;
    out_res[(size_t)row * 128 + nt0 * 16 + c] = acc0[r] + bb0 + prv0[r];
    out_res[(size_t)row * 128 + (nt0 + 1) * 16 + c] = acc1[r] + bb1 + prv1[r];
  }
}

extern "C" void kernel_launch(void* const* d_in, const int* in_sizes, int n_in,
                              void* d_out, int out_size, void* d_ws,
                              size_t ws_size, hipStream_t stream) {
  const float* xyz = (const float*)d_in[0];
  const float* W0a = (const float*)d_in[1];
  const float* b0a = (const float*)d_in[2];
  const float* W0b = (const float*)d_in[3];
  const float* b0b = (const float*)d_in[4];
  const float* W1 = (const float*)d_in[5];
  const float* b1 = (const float*)d_in[6];
  const float* W2 = (const float*)d_in[7];
  const float* b2 = (const float*)d_in[8];
  const float* Wd1 = (const float*)d_in[9];
  const float* bd1 = (const float*)d_in[10];
  const float* Wd2 = (const float*)d_in[11];
  const float* bd2 = (const float*)d_in[12];
  const float* Wg1 = (const float*)d_in[13];
  const float* bg1 = (const float*)d_in[14];
  const float* Wg2 = (const float*)d_in[15];
  const float* bg2 = (const float*)d_in[16];
  const float* Wq = (const float*)d_in[17];
  const float* Wk = (const float*)d_in[18];
  const float* Wv = (const float*)d_in[19];

  char* ws = (char*)d_ws;
  int* knn = (int*)ws;                                  // 1 MB
  float* pre = (float*)(ws + (1 << 20));                // 8 MB
  float* qv = (float*)(ws + (9 << 20));                 // 8 MB
  float* kv = (float*)(ws + (17 << 20));                // 8 MB
  float* vv = (float*)(ws + (25 << 20));                // 8 MB
  float* res_ws = (float*)(ws + (33 << 20));            // 8 MB
  short* wsw = (short*)(ws + (41 << 20));               // 96 KB bf16 B-frags
  short* wsplit = (short*)(ws + (41 << 20) + (128 << 10));  // 384 KB split frags
  float4* pts4 = (float4*)(ws + (42 << 20));            // 256 KB packed points

  float* out_res = (float*)d_out;
  float* out_attn = out_res + (size_t)BN * DD;

  hipLaunchKernelGGL(swz_all_kernel, dim3(72), dim3(256), 0, stream, xyz, Wd2,
                     Wg1, Wg2, W0b, W1, Wq, Wk, Wv, W2, wsw, wsplit, pts4);
  hipLaunchKernelGGL(knn_kernel, dim3(1024), dim3(256), 0, stream, pts4, knn);
  hipLaunchKernelGGL(point_mlp_mfma_kernel, dim3(1024), dim3(256), 0, stream,
                     xyz, W0a, b0a, b0b, b1, wsplit, pre, qv, kv, vv);
  hipLaunchKernelGGL(attn_mfma_kernel, dim3(4096), dim3(256), 0, stream, xyz,
                     knn, qv, kv, vv, wsw, Wd1, bd1, bd2, bg1, bg2, res_ws,
                     out_attn);
  hipLaunchKernelGGL(epilogue_mfma_kernel, dim3(1024), dim3(256), 0, stream,
                     res_ws, wsplit, b2, pre, out_res);
}